// Round 9
// baseline (130.407 us; speedup 1.0000x reference)
//
#include <hip/hip_runtime.h>

#define NSLOPE 0.2f

typedef __attribute__((ext_vector_type(8))) short short8;   // 8 bf16 (4 VGPR) MFMA A/B frag
typedef __attribute__((ext_vector_type(4))) float floatx4;  // MFMA C/D frag

// ---- bf16 helpers (finite values; RNE) ----
static __device__ inline unsigned short f2bf(float f) {
    unsigned u = __float_as_uint(f);
    unsigned r = u + 0x7FFFu + ((u >> 16) & 1u);
    return (unsigned short)(r >> 16);
}
static __device__ inline float bflo(unsigned u) { return __uint_as_float(u << 16); }
static __device__ inline float bfhi(unsigned u) { return __uint_as_float(u & 0xFFFF0000u); }

// ---------------- projection via MFMA: P = bf16(nodes @ Wcat^T) (+bias on first 64 outs) ----------------
#define PNB 128   // nodes per block
#define AST 72    // LDS row stride in ushorts (64 + 8 pad)

__global__ __launch_bounds__(256) void proj_mfma_kernel(
    const float* __restrict__ nodes, const float* __restrict__ Ww,
    const float* __restrict__ Wb,
    unsigned short* __restrict__ P1, unsigned short* __restrict__ P2,
    float* __restrict__ ssum, int nNodes)
{
    __shared__ unsigned short aT[PNB * AST];   // node tile, bf16 [n][k]
    __shared__ unsigned short wT[128 * AST];   // Wcat, bf16 [j][k]: j<64 W1 row j, j>=64 W2 row j-64
    const int t = threadIdx.x;
    const int base = blockIdx.x * PNB;

    // fold ssum zeroing in (compact ssum)
    if (t < PNB) { int n = base + t; if (n < nNodes) ssum[n] = 0.f; }

    // stage nodes -> bf16 LDS
    for (int f = t; f < PNB * 16; f += 256) {
        int n = f >> 4, dpos = (f & 15) * 4;
        float4 v = make_float4(0.f, 0.f, 0.f, 0.f);
        if (base + n < nNodes) v = *(const float4*)(nodes + (size_t)(base + n) * 64 + dpos);
        ushort4 o;
        o.x = f2bf(v.x); o.y = f2bf(v.y); o.z = f2bf(v.z); o.w = f2bf(v.w);
        *(ushort4*)&aT[n * AST + dpos] = o;
    }
    // stage W (f32 -> bf16), Ww is [64][128] row-major: cols 0..63 -> W1, 64..127 -> W2
    for (int i = t; i < 2048; i += 256) {
        float4 v = *(const float4*)(Ww + i * 4);
        int o = i >> 5;            // row of Ww
        int c = (i * 4) & 127;     // col base
        int j, k;
        if (c < 64) { j = o;      k = c;      }
        else        { j = 64 + o; k = c - 64; }
        ushort4 w4;
        w4.x = f2bf(v.x); w4.y = f2bf(v.y); w4.z = f2bf(v.z); w4.w = f2bf(v.w);
        *(ushort4*)&wT[j * AST + k] = w4;
    }
    __syncthreads();

    const int w = t >> 6, lane = t & 63;
    const int lr = lane & 15;
    const int lk = (lane >> 4) * 8;

    floatx4 acc[2][8];
    #pragma unroll
    for (int rt = 0; rt < 2; rt++)
        #pragma unroll
        for (int ct = 0; ct < 8; ct++) acc[rt][ct] = (floatx4){0.f, 0.f, 0.f, 0.f};

    #pragma unroll
    for (int ks = 0; ks < 2; ks++) {
        int k0 = ks * 32 + lk;
        short8 a0 = *(const short8*)&aT[((w * 2 + 0) * 16 + lr) * AST + k0];
        short8 a1 = *(const short8*)&aT[((w * 2 + 1) * 16 + lr) * AST + k0];
        #pragma unroll
        for (int ct = 0; ct < 8; ct++) {
            short8 b = *(const short8*)&wT[(ct * 16 + lr) * AST + k0];
            acc[0][ct] = __builtin_amdgcn_mfma_f32_16x16x32_bf16(a0, b, acc[0][ct], 0, 0, 0);
            acc[1][ct] = __builtin_amdgcn_mfma_f32_16x16x32_bf16(a1, b, acc[1][ct], 0, 0, 0);
        }
    }

    // epilogue: C layout col=lane&15, row=(lane>>4)*4+reg  [m89-verified]
    #pragma unroll
    for (int ct = 0; ct < 8; ct++) {
        int j = ct * 16 + lr;
        float bias = (j < 64) ? Wb[j] : 0.f;
        #pragma unroll
        for (int rt = 0; rt < 2; rt++) {
            #pragma unroll
            for (int r = 0; r < 4; r++) {
                int nl = (w * 2 + rt) * 16 + (lane >> 4) * 4 + r;
                int n = base + nl;
                if (n < nNodes) {
                    unsigned short val = f2bf(acc[rt][ct][r] + bias);
                    if (j < 64) P1[(size_t)n * 64 + j]      = val;
                    else        P2[(size_t)n * 64 + j - 64] = val;
                }
            }
        }
    }
}

// ---------------- per-edge score + exp + segment-sum (software-pipelined grid-stride) ----------------
// One edge per 8-lane group; next iteration's index+row loads issued before the
// current edge's compute -> ~32 gather lines in flight per wave at full occupancy.
__global__ __launch_bounds__(256, 8) void edge_score_kernel(
    const unsigned short* __restrict__ P1, const unsigned short* __restrict__ P2,
    const int* __restrict__ src, const int* __restrict__ dst,
    const float* __restrict__ a_w,
    float* __restrict__ evals, float* __restrict__ ssum, int nE)
{
    const int sub = threadIdx.x & 7;
    const int g0  = blockIdx.x * 32 + (threadIdx.x >> 3);
    const int G   = gridDim.x * 32;

    const float4 a0 = *(const float4*)(a_w + sub * 8);
    const float4 a1 = *(const float4*)(a_w + sub * 8 + 4);

    int e = g0;
    if (e >= nE) return;

    int sCur = src[e];
    int dCur = dst[e];
    uint4 A = *(const uint4*)(P1 + (size_t)sCur * 64 + sub * 8);
    uint4 B = *(const uint4*)(P2 + (size_t)dCur * 64 + sub * 8);

    while (e < nE) {
        const int e2 = e + G;
        int s2 = 0;
        uint4 A2, B2;
        if (e2 < nE) {
            s2 = src[e2];
            int d2 = dst[e2];
            A2 = *(const uint4*)(P1 + (size_t)s2 * 64 + sub * 8);
            B2 = *(const uint4*)(P2 + (size_t)d2 * 64 + sub * 8);
        }

        float p = 0.f, h;
        h = bflo(A.x) + bflo(B.x); h = (h >= 0.f) ? h : NSLOPE * h; p = fmaf(h, a0.x, p);
        h = bfhi(A.x) + bfhi(B.x); h = (h >= 0.f) ? h : NSLOPE * h; p = fmaf(h, a0.y, p);
        h = bflo(A.y) + bflo(B.y); h = (h >= 0.f) ? h : NSLOPE * h; p = fmaf(h, a0.z, p);
        h = bfhi(A.y) + bfhi(B.y); h = (h >= 0.f) ? h : NSLOPE * h; p = fmaf(h, a0.w, p);
        h = bflo(A.z) + bflo(B.z); h = (h >= 0.f) ? h : NSLOPE * h; p = fmaf(h, a1.x, p);
        h = bfhi(A.z) + bfhi(B.z); h = (h >= 0.f) ? h : NSLOPE * h; p = fmaf(h, a1.y, p);
        h = bflo(A.w) + bflo(B.w); h = (h >= 0.f) ? h : NSLOPE * h; p = fmaf(h, a1.z, p);
        h = bfhi(A.w) + bfhi(B.w); h = (h >= 0.f) ? h : NSLOPE * h; p = fmaf(h, a1.w, p);

        p += __shfl_xor(p, 1);
        p += __shfl_xor(p, 2);
        p += __shfl_xor(p, 4);

        if (sub == 0) {
            // max-shift dropped: softmax is shift-invariant and |score| <~ 8 here.
            float ev = __expf(p);
            evals[e] = ev;
            atomicAdd(&ssum[sCur], ev);
        }

        e = e2; sCur = s2; A = A2; B = B2;
    }
}

// ---------------- normalize: attn = eval / ssum[src] (in place in d_out) ----------------
__global__ __launch_bounds__(256) void normalize_kernel(
    const int* __restrict__ src, const float* __restrict__ ssum,
    float* __restrict__ out, int nE)
{
    int i = blockIdx.x * 256 + threadIdx.x;
    int e4 = i * 4;
    if (e4 + 3 < nE) {
        float4 ev = *(const float4*)(out + e4);
        int4   sv = *(const int4*)(src + e4);
        float4 r;
        r.x = ev.x / ssum[sv.x];
        r.y = ev.y / ssum[sv.y];
        r.z = ev.z / ssum[sv.z];
        r.w = ev.w / ssum[sv.w];
        *(float4*)(out + e4) = r;
    } else {
        for (int e = e4; e < nE; ++e) out[e] = out[e] / ssum[src[e]];
    }
}

extern "C" void kernel_launch(void* const* d_in, const int* in_sizes, int n_in,
                              void* d_out, int out_size, void* d_ws, size_t ws_size,
                              hipStream_t stream) {
    (void)n_in; (void)out_size; (void)ws_size;
    const float* nodes = (const float*)d_in[0];
    const int*   src   = (const int*)d_in[1];
    const int*   dst   = (const int*)d_in[2];
    const float* Ww    = (const float*)d_in[3];
    const float* Wb    = (const float*)d_in[4];
    const float* a_w   = (const float*)d_in[5];
    float* out = (float*)d_out;

    const int nNodes = in_sizes[0] / 64;
    const int nE     = in_sizes[1];

    unsigned short* P1   = (unsigned short*)d_ws;              // nN*64 bf16
    unsigned short* P2   = P1 + (size_t)nNodes * 64;           // nN*64 bf16
    float*          ssum = (float*)(P2 + (size_t)nNodes * 64); // nN f32

    int nblocks_proj = (nNodes + PNB - 1) / PNB;
    proj_mfma_kernel<<<nblocks_proj, 256, 0, stream>>>(nodes, Ww, Wb, P1, P2, ssum, nNodes);

    // 2048 blocks = 8192 waves = full 32-wave/CU residency; grid-stride pipeline.
    edge_score_kernel<<<2048, 256, 0, stream>>>(P1, P2, src, dst, a_w, out, ssum, nE);

    int nthreads_norm = (nE + 3) / 4;
    int nblocks_norm  = (nthreads_norm + 255) / 256;
    normalize_kernel<<<nblocks_norm, 256, 0, stream>>>(src, ssum, out, nE);
}

// Round 10
// 115.759 us; speedup vs baseline: 1.1265x; 1.1265x over previous
//
#include <hip/hip_runtime.h>

#define NSLOPE 0.2f

typedef __attribute__((ext_vector_type(8))) short short8;   // 8 bf16 (4 VGPR) MFMA A/B frag
typedef __attribute__((ext_vector_type(4))) float floatx4;  // MFMA C/D frag

// ---- bf16 helpers (finite values; RNE) ----
static __device__ inline unsigned short f2bf(float f) {
    unsigned u = __float_as_uint(f);
    unsigned r = u + 0x7FFFu + ((u >> 16) & 1u);
    return (unsigned short)(r >> 16);
}
static __device__ inline float bflo(unsigned u) { return __uint_as_float(u << 16); }
static __device__ inline float bfhi(unsigned u) { return __uint_as_float(u & 0xFFFF0000u); }

// ---------------- projection via MFMA: P = bf16(nodes @ Wcat^T) (+bias on first 64 outs) ----------------
#define PNB 128   // nodes per block
#define AST 72    // staging LDS row stride in ushorts (64 + 8 pad)
#define CST 136   // epilogue LDS row stride in ushorts (128 + 8 pad)

__global__ __launch_bounds__(256) void proj_mfma_kernel(
    const float* __restrict__ nodes, const float* __restrict__ Ww,
    const float* __restrict__ Wb,
    unsigned short* __restrict__ P1, unsigned short* __restrict__ P2,
    float* __restrict__ ssum, int nNodes)
{
    // one buffer, two lives: [staging: aT(128x72) | wT(128x72)] then [epilogue: cT(128x136)]
    __shared__ unsigned short S[2 * PNB * AST];   // 36864 ushorts = 73728 B... (see note: 2*128*72=18432 ushorts=36.9KB)
    unsigned short* aT = S;                 // [n][k], 128x72
    unsigned short* wT = S + PNB * AST;     // [j][k], 128x72
    unsigned short* cT = S;                 // [n][j], 128x136 (17408 <= 18432 ushorts)
    const int t = threadIdx.x;
    const int base = blockIdx.x * PNB;

    // fold ssum zeroing in (compact ssum)
    if (t < PNB) { int n = base + t; if (n < nNodes) ssum[n] = 0.f; }

    // stage nodes -> bf16 LDS
    for (int f = t; f < PNB * 16; f += 256) {
        int n = f >> 4, dpos = (f & 15) * 4;
        float4 v = make_float4(0.f, 0.f, 0.f, 0.f);
        if (base + n < nNodes) v = *(const float4*)(nodes + (size_t)(base + n) * 64 + dpos);
        ushort4 o;
        o.x = f2bf(v.x); o.y = f2bf(v.y); o.z = f2bf(v.z); o.w = f2bf(v.w);
        *(ushort4*)&aT[n * AST + dpos] = o;
    }
    // stage W (f32 -> bf16), Ww is [64][128] row-major: cols 0..63 -> W1, 64..127 -> W2
    for (int i = t; i < 2048; i += 256) {
        float4 v = *(const float4*)(Ww + i * 4);
        int o = i >> 5;            // row of Ww
        int c = (i * 4) & 127;     // col base
        int j, k;
        if (c < 64) { j = o;      k = c;      }
        else        { j = 64 + o; k = c - 64; }
        ushort4 w4;
        w4.x = f2bf(v.x); w4.y = f2bf(v.y); w4.z = f2bf(v.z); w4.w = f2bf(v.w);
        *(ushort4*)&wT[j * AST + k] = w4;
    }
    __syncthreads();

    const int w = t >> 6, lane = t & 63;
    const int lr = lane & 15;
    const int lk = (lane >> 4) * 8;

    floatx4 acc[2][8];
    #pragma unroll
    for (int rt = 0; rt < 2; rt++)
        #pragma unroll
        for (int ct = 0; ct < 8; ct++) acc[rt][ct] = (floatx4){0.f, 0.f, 0.f, 0.f};

    #pragma unroll
    for (int ks = 0; ks < 2; ks++) {
        int k0 = ks * 32 + lk;
        short8 a0 = *(const short8*)&aT[((w * 2 + 0) * 16 + lr) * AST + k0];
        short8 a1 = *(const short8*)&aT[((w * 2 + 1) * 16 + lr) * AST + k0];
        #pragma unroll
        for (int ct = 0; ct < 8; ct++) {
            short8 b = *(const short8*)&wT[(ct * 16 + lr) * AST + k0];
            acc[0][ct] = __builtin_amdgcn_mfma_f32_16x16x32_bf16(a0, b, acc[0][ct], 0, 0, 0);
            acc[1][ct] = __builtin_amdgcn_mfma_f32_16x16x32_bf16(a1, b, acc[1][ct], 0, 0, 0);
        }
    }

    // ---- epilogue via LDS transpose for coalesced 16B stores ----
    __syncthreads();   // all MFMA reads of aT/wT done before overwrite

    // C layout col=lane&15, row=(lane>>4)*4+reg [m89-verified]:
    // node nl = (w*2+rt)*16 + (lane>>4)*4 + r, out col j = ct*16 + lr
    #pragma unroll
    for (int ct = 0; ct < 8; ct++) {
        int j = ct * 16 + lr;
        float bias = (ct < 4) ? Wb[j] : 0.f;
        #pragma unroll
        for (int rt = 0; rt < 2; rt++) {
            int nbase = (w * 2 + rt) * 16 + (lane >> 4) * 4;
            #pragma unroll
            for (int r = 0; r < 4; r++)
                cT[(nbase + r) * CST + j] = f2bf(acc[rt][ct][r] + bias);
        }
    }
    __syncthreads();

    // coalesced stores: 1024 16B-chunks per array; consecutive lanes -> consecutive 16B
    for (int i = t; i < 1024; i += 256) {
        int n = i >> 3, c8 = (i & 7) * 8;
        if (base + n < nNodes) {
            uint4 v1 = *(const uint4*)&cT[n * CST + c8];
            *(uint4*)(P1 + (size_t)(base + n) * 64 + c8) = v1;
        }
    }
    for (int i = t; i < 1024; i += 256) {
        int n = i >> 3, c8 = (i & 7) * 8;
        if (base + n < nNodes) {
            uint4 v2 = *(const uint4*)&cT[n * CST + 64 + c8];
            *(uint4*)(P2 + (size_t)(base + n) * 64 + c8) = v2;
        }
    }
}

// ---------------- per-edge score + exp + segment-sum ----------------
// 8 lanes per edge; each lane handles 8 dims (16 B bf16 loads, fully coalesced
// 128 B per gathered row). Round-8 exact (best measured: 88.4 us).
__global__ __launch_bounds__(256) void edge_score_kernel(
    const unsigned short* __restrict__ P1, const unsigned short* __restrict__ P2,
    const int* __restrict__ src, const int* __restrict__ dst,
    const float* __restrict__ a_w,
    float* __restrict__ evals, float* __restrict__ ssum, int nE)
{
    int tid = blockIdx.x * 256 + threadIdx.x;
    int e   = tid >> 3;
    int sub = tid & 7;
    if (e >= nE) return;

    int s = src[e];
    int d = dst[e];
    uint4 r1 = *(const uint4*)(P1 + (size_t)s * 64 + sub * 8);
    uint4 r2 = *(const uint4*)(P2 + (size_t)d * 64 + sub * 8);
    float4 a0 = *(const float4*)(a_w + sub * 8);
    float4 a1 = *(const float4*)(a_w + sub * 8 + 4);

    float partial = 0.f, h;
    h = bflo(r1.x) + bflo(r2.x); h = (h >= 0.f) ? h : NSLOPE * h; partial = fmaf(h, a0.x, partial);
    h = bfhi(r1.x) + bfhi(r2.x); h = (h >= 0.f) ? h : NSLOPE * h; partial = fmaf(h, a0.y, partial);
    h = bflo(r1.y) + bflo(r2.y); h = (h >= 0.f) ? h : NSLOPE * h; partial = fmaf(h, a0.z, partial);
    h = bfhi(r1.y) + bfhi(r2.y); h = (h >= 0.f) ? h : NSLOPE * h; partial = fmaf(h, a0.w, partial);
    h = bflo(r1.z) + bflo(r2.z); h = (h >= 0.f) ? h : NSLOPE * h; partial = fmaf(h, a1.x, partial);
    h = bfhi(r1.z) + bfhi(r2.z); h = (h >= 0.f) ? h : NSLOPE * h; partial = fmaf(h, a1.y, partial);
    h = bflo(r1.w) + bflo(r2.w); h = (h >= 0.f) ? h : NSLOPE * h; partial = fmaf(h, a1.z, partial);
    h = bfhi(r1.w) + bfhi(r2.w); h = (h >= 0.f) ? h : NSLOPE * h; partial = fmaf(h, a1.w, partial);

    partial += __shfl_xor(partial, 1);
    partial += __shfl_xor(partial, 2);
    partial += __shfl_xor(partial, 4);

    if (sub == 0) {
        // max-shift dropped: softmax is shift-invariant and |score| <~ 8 here.
        float ev = __expf(partial);
        evals[e] = ev;
        atomicAdd(&ssum[s], ev);
    }
}

// ---------------- normalize: attn = eval / ssum[src] (in place in d_out) ----------------
__global__ __launch_bounds__(256) void normalize_kernel(
    const int* __restrict__ src, const float* __restrict__ ssum,
    float* __restrict__ out, int nE)
{
    int i = blockIdx.x * 256 + threadIdx.x;
    int e4 = i * 4;
    if (e4 + 3 < nE) {
        float4 ev = *(const float4*)(out + e4);
        int4   sv = *(const int4*)(src + e4);
        float4 r;
        r.x = ev.x / ssum[sv.x];
        r.y = ev.y / ssum[sv.y];
        r.z = ev.z / ssum[sv.z];
        r.w = ev.w / ssum[sv.w];
        *(float4*)(out + e4) = r;
    } else {
        for (int e = e4; e < nE; ++e) out[e] = out[e] / ssum[src[e]];
    }
}

extern "C" void kernel_launch(void* const* d_in, const int* in_sizes, int n_in,
                              void* d_out, int out_size, void* d_ws, size_t ws_size,
                              hipStream_t stream) {
    (void)n_in; (void)out_size; (void)ws_size;
    const float* nodes = (const float*)d_in[0];
    const int*   src   = (const int*)d_in[1];
    const int*   dst   = (const int*)d_in[2];
    const float* Ww    = (const float*)d_in[3];
    const float* Wb    = (const float*)d_in[4];
    const float* a_w   = (const float*)d_in[5];
    float* out = (float*)d_out;

    const int nNodes = in_sizes[0] / 64;
    const int nE     = in_sizes[1];

    unsigned short* P1   = (unsigned short*)d_ws;              // nN*64 bf16
    unsigned short* P2   = P1 + (size_t)nNodes * 64;           // nN*64 bf16
    float*          ssum = (float*)(P2 + (size_t)nNodes * 64); // nN f32

    int nblocks_proj = (nNodes + PNB - 1) / PNB;
    proj_mfma_kernel<<<nblocks_proj, 256, 0, stream>>>(nodes, Ww, Wb, P1, P2, ssum, nNodes);

    int nblocks_edge = (int)(((long long)nE * 8 + 255) / 256);
    edge_score_kernel<<<nblocks_edge, 256, 0, stream>>>(P1, P2, src, dst, a_w, out, ssum, nE);

    int nthreads_norm = (nE + 3) / 4;
    int nblocks_norm  = (nthreads_norm + 255) / 256;
    normalize_kernel<<<nblocks_norm, 256, 0, stream>>>(src, ssum, out, nE);
}